// Round 7
// baseline (314.839 us; speedup 1.0000x reference)
//
#include <hip/hip_runtime.h>
#include <stdint.h>

typedef unsigned long long u64;
typedef unsigned int u32;

#define N_BOXES 50000
#define N_CLS 80
#define N_IMG 8
#define KCAND 500
#define MAX_DET 300
#define CAP 1024          // per-class per-image candidates: mean 692, sigma 26 -> +12.7 sigma
#define PRE_THR 0.8f

#define P_BOXES 512
#define NGRP ((N_BOXES + P_BOXES - 1) / P_BOXES)  // 98
#define SLOT 48           // per-class per-block cap: lambda 7.09, P(>=48) ~ e^-52

// workspace layout (bytes)
#define OFF_CANDCNT 0                      // 640*4 -> 2560
#define OFF_KEPTCNT 2560                   // 640*4 -> 5120
#define OFF_IMGHIST 8192                   // 8*2048*4 = 65536 -> 73728
#define OFF_KEPTKEYS 73728                 // 640*512*8 = 2621440 -> 2695168
#define OFF_CAND 2695168                   // 640*1024*8 = 5242880 -> 7938048

__device__ __forceinline__ int bin_of(u32 sb) {
  int d = (int)(sb - 0x3F000000u);
  int bin = d < 0 ? 0 : (d >> 12);
  return bin > 2047 ? 2047 : bin;
}

__device__ __forceinline__ u64 shflx64(u64 v, int m) {
  int lo = __shfl_xor((int)(u32)v, m, 64);
  int hi = __shfl_xor((int)(v >> 32), m, 64);
  return ((u64)(u32)hi << 32) | (u32)lo;
}

__device__ __forceinline__ u64 wave_or64(u64 v) {
  for (int m = 1; m < 64; m <<= 1) v |= shflx64(v, m);
  return v;
}

__device__ __forceinline__ void bstep(u64& v, u64 o, int idx, int k, int j) {
  bool takeMax = (((idx & k) == 0) == ((idx & j) == 0));
  if (takeMax ? (o > v) : (o < v)) v = o;
}

// 1024-elt descending bitonic over 512 threads, 2 elts/thread (vL=idx t, vU=idx t+512).
// j==512 is a register step; 64<=j<=256 LDS; j<64 shuffles.
// Top-512-only tail (verified round 6): after the k=1024, j=512 register exchange,
// vL holds the top-512 (bitonic, closed under t^j for j<512), so the remaining
// stages skip all vU work (vU is never read after return).
__device__ __forceinline__ void sort1024_2elt(u64& vL, u64& vU, u64* sbuf, int t) {
  for (int k = 2; k <= 1024; k <<= 1)
    for (int j = k >> 1; j > 0; j >>= 1) {
      if (j == 512) {
        if (vU > vL) { u64 tmp = vL; vL = vU; vU = tmp; }
      } else if (j >= 64) {
        __syncthreads();
        sbuf[t] = vL;
        if (k < 1024) sbuf[t + 512] = vU;
        __syncthreads();
        u64 oL = sbuf[t ^ j];
        bstep(vL, oL, t, k, j);
        if (k < 1024) {
          u64 oU = sbuf[(t ^ j) + 512];
          bstep(vU, oU, t + 512, k, j);
        }
      } else {
        bstep(vL, shflx64(vL, j), t, k, j);
        if (k < 1024) bstep(vU, shflx64(vU, j), t + 512, k, j);
      }
    }
}

// 1-elt/thread hybrid sort (used by k3)
template <int S>
__device__ __forceinline__ void hybrid_sort(u64& v, u64* sbuf, int tid) {
  for (int k = 2; k <= S; k <<= 1)
    for (int j = k >> 1; j > 0; j >>= 1) {
      u64 o;
      if (j >= 64) {
        __syncthreads();
        sbuf[tid] = v;
        __syncthreads();
        o = sbuf[tid ^ j];
      } else {
        o = shflx64(v, j);
      }
      bool takeMax = (((tid & k) == 0) == ((tid & j) == 0));
      if (takeMax ? (o > v) : (o < v)) v = o;
    }
}

template <int T>
__device__ __forceinline__ void pick_threshold(u32* hist, int* partial, int* s_t, int K, int tid) {
  constexpr int G = 2048 / T;
  int ps = 0;
#pragma unroll
  for (int q = 0; q < G; ++q) ps += (int)hist[tid * G + q];
  partial[tid] = ps;
  for (int off = 1; off < T; off <<= 1) {
    __syncthreads();
    int v = partial[tid];
    if (tid + off < T) v += partial[tid + off];
    __syncthreads();
    partial[tid] = v;
  }
  if (tid == 0) *s_t = 0;
  __syncthreads();
  int sfx = partial[tid];
  int nxt = (tid == T - 1) ? 0 : partial[tid + 1];
  if (sfx >= K && nxt < K) {
    int acc = nxt;
    int bin;
    for (bin = tid * G + G - 1; bin > tid * G; --bin) {
      if (acc + (int)hist[bin] >= K) break;
      acc += (int)hist[bin];
    }
    *s_t = bin;
  }
  __syncthreads();
}

// exact RN(inter/denom) > 0.5 with guard band + rare exact-div fallback
// (reference RN op order preserved: denom = ((ai+aj) - inter) + 1e-9)
__device__ __forceinline__ bool iou_sup(float4 bi, float4 bj) {
  float ai = __fmul_rn(fmaxf(__fsub_rn(bi.z, bi.x), 0.f), fmaxf(__fsub_rn(bi.w, bi.y), 0.f));
  float aj = __fmul_rn(fmaxf(__fsub_rn(bj.z, bj.x), 0.f), fmaxf(__fsub_rn(bj.w, bj.y), 0.f));
  float ih = fmaxf(__fsub_rn(fminf(bi.z, bj.z), fmaxf(bi.x, bj.x)), 0.f);
  float iw = fmaxf(__fsub_rn(fminf(bi.w, bj.w), fmaxf(bi.y, bj.y)), 0.f);
  float inter = __fmul_rn(ih, iw);
  float denom = __fadd_rn(__fsub_rn(__fadd_rn(ai, aj), inter), 1e-9f);
  float diff = __fsub_rn(__fmul_rn(inter, 2.f), denom);
  if (fabsf(diff) > __fmul_rn(denom, 1e-6f)) return diff > 0.f;
  return __fdiv_rn(inter, denom) > 0.5f;
}

// ---------------- kernel 1: candidate compaction (per-class LDS buffers) ----------------
// key = score_bits<<32 | (~n & 0xFFFF)<<16 | c   (c constant within a class sort)
// Per passing score: one LDS atomic on cnt[c] + one LDS store (lgkmcnt path, leaves
// the vmcnt load pipeline free — round-4 lesson). Round-5 proven form (round-6
// 4-deep batching regressed; reverted).
__global__ __launch_bounds__(512) void k1_compact(const float* __restrict__ cls,
                                                  int* __restrict__ candCnt,
                                                  u64* __restrict__ cand) {
  __shared__ u64 bkeyc[N_CLS * SLOT];   // 30720 B
  __shared__ int cnt[N_CLS];
  __shared__ int cbase[N_CLS];

  int tid = threadIdx.x;
  int b = blockIdx.x / NGRP, g = blockIdx.x % NGRP;
  int n0 = g * P_BOXES;
  int nb = N_BOXES - n0;
  if (nb > P_BOXES) nb = P_BOXES;
  int nf4 = nb * (N_CLS / 4);
  const float4* src = (const float4*)(cls + ((size_t)b * N_BOXES + n0) * N_CLS);

  if (tid < N_CLS) cnt[tid] = 0;
  __syncthreads();

  // 1 float4/thread/iter: lane addresses are 16B-contiguous -> perfectly coalesced.
  // Common case (94%) is pure load+4cmp; passer path is rare and off the load chain.
  for (int i = tid; i < nf4; i += 512) {
    float4 s4 = src[i];
    bool p0 = s4.x > PRE_THR, p1 = s4.y > PRE_THR, p2 = s4.z > PRE_THR, p3 = s4.w > PRE_THR;
    if (p0 | p1 | p2 | p3) {
      int nl = i / 20;               // 20 float4 per 80-class row
      int cb = (i - nl * 20) * 4;
      u64 pk = (u64)((((u32)(~(u32)(n0 + nl)) & 0xFFFFu) << 16));
      if (p0) {
        int s = atomicAdd(&cnt[cb + 0], 1);
        if (s < SLOT) bkeyc[(cb + 0) * SLOT + s] = ((u64)__float_as_uint(s4.x) << 32) | pk | (u32)(cb + 0);
      }
      if (p1) {
        int s = atomicAdd(&cnt[cb + 1], 1);
        if (s < SLOT) bkeyc[(cb + 1) * SLOT + s] = ((u64)__float_as_uint(s4.y) << 32) | pk | (u32)(cb + 1);
      }
      if (p2) {
        int s = atomicAdd(&cnt[cb + 2], 1);
        if (s < SLOT) bkeyc[(cb + 2) * SLOT + s] = ((u64)__float_as_uint(s4.z) << 32) | pk | (u32)(cb + 2);
      }
      if (p3) {
        int s = atomicAdd(&cnt[cb + 3], 1);
        if (s < SLOT) bkeyc[(cb + 3) * SLOT + s] = ((u64)__float_as_uint(s4.w) << 32) | pk | (u32)(cb + 3);
      }
    }
  }
  __syncthreads();
  if (tid < N_CLS) {
    int n = cnt[tid];
    if (n > SLOT) n = SLOT;
    cnt[tid] = n;
    cbase[tid] = n ? atomicAdd(&candCnt[b * N_CLS + tid], n) : 0;
  }
  __syncthreads();
  for (int i = tid; i < N_CLS * SLOT; i += 512) {
    int c = i / SLOT, s = i - c * SLOT;
    if (s < cnt[c]) {
      int pos = cbase[c] + s;
      if (pos < CAP) cand[(size_t)(b * N_CLS + c) * CAP + pos] = bkeyc[i];
    }
  }
}

// eager tiles: (jb, w), w <= jb, jb <= 4  (15 tiles) -- covers the scan's usual reach
// (total hits 300 inside chunk 4 at ~95% keep); chunks 5-7 use the rare fallback.
// Max 2 tiles/wave (round-6 pairing broke this balance; reverted).
__device__ const unsigned char TJB[15] = {0, 1,1, 2,2,2, 3,3,3,3, 4,4,4,4,4};
__device__ const unsigned char TW[15]  = {0, 0,1, 0,1,2, 0,1,2,3, 0,1,2,3,4};

#define COLS_STRIDE 320

// Broadcast via v_readlane, not LDS (round-6 lesson: k2 is DS-pipe-bound, not VALU).
// Each lane pre-loads its slot of the w-row (rowb/rowa: one b128 + one b32 per tile);
// the 64-iter loop pulls bi/ai with readlane(.., il) — il is an unroll constant, so
// this is 5 VALU readlanes/iter and ZERO DS ops (was 64 b128 + 64 b32 per tile).
// Readlane ignores exec and returns exact bits -> math bit-identical to round 3.
template <bool DIAG>
__device__ __forceinline__ void mask_tile(const float4* bx, const float* areas, u64* cols,
                                          int jb, int w, int lane, int V) {
  float4 rowb = bx[w * 64 + lane];   // loaded by ALL lanes (pre-divergence)
  float rowa = areas[w * 64 + lane];
  int j = jb * 64 + lane;
  u64 sup = 0;
  if (j < V) {
    float4 bj = bx[j];
    float aj = areas[j];
    u64 needs = 0;
#pragma unroll
    for (int il = 0; il < 64; ++il) {
      float bix = __uint_as_float(__builtin_amdgcn_readlane(__float_as_uint(rowb.x), il));
      float biy = __uint_as_float(__builtin_amdgcn_readlane(__float_as_uint(rowb.y), il));
      float biz = __uint_as_float(__builtin_amdgcn_readlane(__float_as_uint(rowb.z), il));
      float biw = __uint_as_float(__builtin_amdgcn_readlane(__float_as_uint(rowb.w), il));
      float ai  = __uint_as_float(__builtin_amdgcn_readlane(__float_as_uint(rowa), il));
      float yy1 = fmaxf(bix, bj.x);
      float xx1 = fmaxf(biy, bj.y);
      float yy2 = fminf(biz, bj.z);
      float xx2 = fminf(biw, bj.w);
      float ih = fmaxf(__fsub_rn(yy2, yy1), 0.0f);
      float iw = fmaxf(__fsub_rn(xx2, xx1), 0.0f);
      float inter = __fmul_rn(ih, iw);
      float denom = __fadd_rn(__fsub_rn(__fadd_rn(ai, aj), inter), 1e-9f);
      float diff = __fsub_rn(__fmul_rn(inter, 2.0f), denom);
      bool fast = diff > 0.0f;
      bool nd = fabsf(diff) <= __fmul_rn(denom, 1e-6f);
      if (DIAG) { bool lt = il < lane; fast = fast && lt; nd = nd && lt; }
      sup |= fast ? (1ull << il) : 0ull;
      needs |= nd ? (1ull << il) : 0ull;
    }
    if (needs) {
      const float4* bp = bx + w * 64;  // rare exact path: LDS read is fine
      u64 nm = needs;
      while (nm) {
        int il = __builtin_ctzll(nm);
        nm &= nm - 1;
        if (iou_sup(bp[il], bj)) sup |= (1ull << il);
        else sup &= ~(1ull << il);
      }
    }
  }
  cols[w * COLS_STRIDE + jb * 64 + lane] = sup;
}

// common tail of a scan chunk: greedy in-chunk propagation + kept-key write
#define SCAN_TAIL(dstc)                                                            \
    u64 supmask = __ballot(sup);                                                   \
    u64 anysup = wave_or64(colw);                                                  \
    u64 rem = anysup & ~supmask;                                                   \
    while (rem) {                                                                  \
      int i = __builtin_ctzll(rem);                                                \
      rem &= rem - 1;                                                              \
      if (!((supmask >> i) & 1ull)) {                                              \
        supmask |= __ballot((int)((colw >> i) & 1ull));                            \
        rem &= ~supmask;                                                           \
      }                                                                            \
    }                                                                              \
    int lim = V - (dstc) * 64;                                                     \
    if (lim > 64) lim = 64;                                                        \
    u64 valid = (lim >= 64) ? ~0ull : ((1ull << lim) - 1ull);                      \
    u64 keptm = ~supmask & valid;                                                  \
    int rank = total + (int)__builtin_popcountll(keptm & ((1ull << lane) - 1ull)); \
    if (((keptm >> lane) & 1ull) && rank < MAX_DET) {                              \
      u64 key = sbuf[gj];                                                          \
      u32 sb = (u32)(key >> 32);                                                   \
      u32 n = (~(u32)(key >> 16)) & 0xFFFFu;                                       \
      u32 flat = (u32)(c * KCAND + gj);                                            \
      keptKeys[(size_t)bc * 512 + rank] =                                          \
          ((u64)sb << 32) | ((u64)((~flat) & 0xFFFFu) << 16) | (u64)n;             \
      atomicAdd(&imgHist[b * 2048 + bin_of(sb)], 1u);                              \
    }                                                                              \
    total += (int)__builtin_popcountll(keptm);                                     \
    kmreg[dstc] = keptm;

// cols-based chunk (dstc <= 4); dstc compile-time so kmreg stays in registers
#define SCAN_CHUNK(dstc)                                                           \
  if ((dstc) * 64 < V && total < MAX_DET) {                                        \
    int gj = (dstc) * 64 + lane;                                                   \
    bool sup = false;                                                              \
    _Pragma("unroll")                                                              \
    for (int src = 0; src < (dstc); ++src)                                         \
      if (cols[src * COLS_STRIDE + gj] & kmreg[src]) sup = true;                   \
    u64 colw = cols[(dstc) * COLS_STRIDE + gj];                                    \
    SCAN_TAIL(dstc)                                                                \
  }

// on-the-fly fallback chunk (dstc >= 5): almost always skipped (total >= 300)
#define SCAN_CHUNK_FB(dstc)                                                        \
  if ((dstc) * 64 < V && total < MAX_DET) {                                        \
    int gj = (dstc) * 64 + lane;                                                   \
    bool act = gj < V;                                                             \
    float4 bg = bx[act ? gj : 0];                                                  \
    bool sup = false;                                                              \
    u64 colw = 0;                                                                  \
    _Pragma("unroll")                                                              \
    for (int src = 0; src < (dstc); ++src) {                                       \
      u64 km = kmreg[src];                                                         \
      while (km) {                                                                 \
        int i = __builtin_ctzll(km);                                               \
        km &= km - 1;                                                              \
        if (act && iou_sup(bx[src * 64 + i], bg)) sup = true;                      \
      }                                                                            \
    }                                                                              \
    for (int il = 0; il < 64; ++il)                                                \
      if (il < lane && act && iou_sup(bx[(dstc) * 64 + il], bg)) colw |= (1ull << il); \
    SCAN_TAIL(dstc)                                                                \
  }

// ---------------- kernel 2: sort-all + NMS ----------------
__global__ __launch_bounds__(512) void k2_class(const float* __restrict__ boxes,
                                                const int* __restrict__ candCnt,
                                                const u64* __restrict__ cand,
                                                int* __restrict__ keptCnt,
                                                u64* __restrict__ keptKeys,
                                                u32* __restrict__ imgHist) {
  __shared__ u64 sbuf[1024];            // 8 KB
  __shared__ float4 bx[512];            // 8 KB
  __shared__ float areas[512];          // 2 KB
  __shared__ u64 cols[5 * COLS_STRIDE]; // 12.8 KB -> total ~31 KB, 5 blocks/CU
  int tid = threadIdx.x;
  int lane = tid & 63, wave = tid >> 6;
  int bc = blockIdx.x;
  int b = bc / N_CLS, c = bc % N_CLS;
  int m = candCnt[bc];
  if (m > CAP) m = CAP;
  const u64* my = cand + (size_t)bc * CAP;

  u64 vL = (tid < m) ? my[tid] : 0;
  u64 vU = (tid + 512 < m) ? my[tid + 512] : 0;
  sort1024_2elt(vL, vU, sbuf, tid);   // vL = rank-tid element (descending)

  int V = m < KCAND ? m : KCAND;
  __syncthreads();
  sbuf[tid] = vL;  // ranks 0..511 (only <V used)
  float4 bxv = make_float4(0.f, 0.f, 0.f, 0.f);
  float av = 0.f;
  if (tid < V) {
    u32 n = (~(u32)(vL >> 16)) & 0xFFFFu;
    bxv = *(const float4*)(boxes + ((size_t)b * N_BOXES + n) * 4);
    av = __fmul_rn(fmaxf(__fsub_rn(bxv.z, bxv.x), 0.f), fmaxf(__fsub_rn(bxv.w, bxv.y), 0.f));
  }
  bx[tid] = bxv;
  areas[tid] = av;
  __syncthreads();

  // 15 eager mask tiles over 8 waves (<=2 tiles/wave)
  for (int idx = wave; idx < 15; idx += 8) {
    int jb = TJB[idx], w = TW[idx];
    if (w == jb) mask_tile<true>(bx, areas, cols, jb, w, lane, V);
    else mask_tile<false>(bx, areas, cols, jb, w, lane, V);
  }
  __syncthreads();

  // greedy scan, wave 0: chunks 0-4 from cols, 5-7 on-the-fly (rarely reached)
  if (tid < 64) {
    u64 kmreg[8];
    int total = 0;
    SCAN_CHUNK(0)
    SCAN_CHUNK(1)
    SCAN_CHUNK(2)
    SCAN_CHUNK(3)
    SCAN_CHUNK(4)
    SCAN_CHUNK_FB(5)
    SCAN_CHUNK_FB(6)
    SCAN_CHUNK_FB(7)
    if (lane == 0) keptCnt[bc] = total < MAX_DET ? total : MAX_DET;
  }
}

// ---------------- kernel 3: per-image global top-300 ----------------
__global__ __launch_bounds__(1024) void k3_image(const float* __restrict__ boxes,
                                                 const int* __restrict__ keptCnt,
                                                 const u64* __restrict__ keptKeys,
                                                 const u32* __restrict__ imgHist,
                                                 float* __restrict__ out) {
  __shared__ u32 hist[2048];
  __shared__ int partial[1024];
  __shared__ u64 sbuf[1024];
  __shared__ int kcs[N_CLS];
  __shared__ int s_t, s_cnt;
  int tid = threadIdx.x;
  int b = blockIdx.x;
  for (int i = tid; i < 2048; i += 1024) hist[i] = imgHist[b * 2048 + i];
  if (tid < N_CLS) kcs[tid] = keptCnt[b * N_CLS + tid];
  if (tid == 0) s_cnt = 0;
  __syncthreads();
  pick_threshold<1024>(hist, partial, &s_t, MAX_DET, tid);
  int t = s_t;
  const u64* kk = keptKeys + (size_t)b * N_CLS * 512;
  for (int idx = tid; idx < N_CLS * 512; idx += 1024) {
    int cc = idx >> 9, k = idx & 511;
    if (k < kcs[cc]) {
      u64 key = kk[(size_t)cc * 512 + k];
      if (bin_of((u32)(key >> 32)) >= t) {
        int p = atomicAdd(&s_cnt, 1);
        if (p < 1024) sbuf[p] = key;
      }
    }
  }
  __syncthreads();
  int cnt = s_cnt;
  if (cnt > 1024) cnt = 1024;
  u64 v = (tid < cnt) ? sbuf[tid] : 0;
  hybrid_sort<1024>(v, sbuf, tid);

  int V = cnt < MAX_DET ? cnt : MAX_DET;
  if (tid < MAX_DET) {
    float o0 = -1.f, o1 = -1.f, o2 = -1.f, o3 = -1.f, osc = -1.f, olb = -1.f;
    if (tid < V) {
      u32 sb = (u32)(v >> 32);
      u32 flat = (~((u32)(v >> 16))) & 0xFFFFu;
      u32 n = (u32)v & 0xFFFFu;
      const float* bp = boxes + ((size_t)b * N_BOXES + n) * 4;
      o0 = bp[0]; o1 = bp[1]; o2 = bp[2]; o3 = bp[3];
      osc = __uint_as_float(sb);
      olb = (float)(flat / KCAND);
    }
    size_t bs = (size_t)b * MAX_DET + tid;
    out[bs * 4 + 0] = o0;
    out[bs * 4 + 1] = o1;
    out[bs * 4 + 2] = o2;
    out[bs * 4 + 3] = o3;
    out[(size_t)N_IMG * MAX_DET * 4 + bs] = osc;
    out[(size_t)N_IMG * MAX_DET * 5 + bs] = olb;
  }
}

extern "C" void kernel_launch(void* const* d_in, const int* in_sizes, int n_in,
                              void* d_out, int out_size, void* d_ws, size_t ws_size,
                              hipStream_t stream) {
  const float* boxes = (const float*)d_in[0];
  const float* cls = (const float*)d_in[1];
  float* out = (float*)d_out;
  char* ws = (char*)d_ws;
  int* candCnt = (int*)(ws + OFF_CANDCNT);
  int* keptCnt = (int*)(ws + OFF_KEPTCNT);
  u32* imgHist = (u32*)(ws + OFF_IMGHIST);
  u64* keptKeys = (u64*)(ws + OFF_KEPTKEYS);
  u64* cand = (u64*)(ws + OFF_CAND);

  hipMemsetAsync(ws, 0, 73728, stream);  // candCnt + keptCnt + imgHist

  k1_compact<<<N_IMG * NGRP, 512, 0, stream>>>(cls, candCnt, cand);
  k2_class<<<N_IMG * N_CLS, 512, 0, stream>>>(boxes, candCnt, cand, keptCnt, keptKeys, imgHist);
  k3_image<<<N_IMG, 1024, 0, stream>>>(boxes, keptCnt, keptKeys, imgHist, out);
}

// Round 8
// 283.279 us; speedup vs baseline: 1.1114x; 1.1114x over previous
//
#include <hip/hip_runtime.h>
#include <stdint.h>

typedef unsigned long long u64;
typedef unsigned int u32;

#define N_BOXES 50000
#define N_CLS 80
#define N_IMG 8
#define KCAND 500
#define MAX_DET 300
#define CAP 1024          // per-class per-image candidates: mean 692, sigma 26 -> +12.7 sigma
#define PRE_THR 0.8f

#define P_BOXES 512
#define NGRP ((N_BOXES + P_BOXES - 1) / P_BOXES)  // 98
#define SLOT 48           // per-class per-block cap: lambda 7.09, P(>=48) ~ e^-52

// workspace layout (bytes)
#define OFF_CANDCNT 0                      // 640*4 -> 2560
#define OFF_KEPTCNT 2560                   // 640*4 -> 5120
#define OFF_IMGCNT 5120                    // 8*4 -> 5152 (inside zeroed region)
#define OFF_IMGHIST 8192                   // 8*2048*4 = 65536 -> 73728
#define OFF_KEPTKEYS 73728                 // 640*512*8 = 2621440 -> 2695168
#define OFF_CAND 2695168                   // 640*1024*8 = 5242880 -> 7938048
#define OFF_IMGCAND 7938048                // 8*1024*8 = 65536 -> 8003584

__device__ __forceinline__ int bin_of(u32 sb) {
  int d = (int)(sb - 0x3F000000u);
  int bin = d < 0 ? 0 : (d >> 12);
  return bin > 2047 ? 2047 : bin;
}

__device__ __forceinline__ u64 shflx64(u64 v, int m) {
  int lo = __shfl_xor((int)(u32)v, m, 64);
  int hi = __shfl_xor((int)(v >> 32), m, 64);
  return ((u64)(u32)hi << 32) | (u32)lo;
}

__device__ __forceinline__ u64 wave_or64(u64 v) {
  for (int m = 1; m < 64; m <<= 1) v |= shflx64(v, m);
  return v;
}

__device__ __forceinline__ void bstep(u64& v, u64 o, int idx, int k, int j) {
  bool takeMax = (((idx & k) == 0) == ((idx & j) == 0));
  if (takeMax ? (o > v) : (o < v)) v = o;
}

// 1024-elt descending bitonic over 512 threads, 2 elts/thread (vL=idx t, vU=idx t+512).
// j==512 is a register step; 64<=j<=256 LDS; j<64 shuffles.
// Top-512-only tail (refchecked rounds 6,7): after the k=1024, j=512 register
// exchange, vL holds the top-512 (bitonic, closed under t^j for j<512); the
// remaining stages skip all vU work (vU never read after return).
__device__ __forceinline__ void sort1024_2elt(u64& vL, u64& vU, u64* sbuf, int t) {
  for (int k = 2; k <= 1024; k <<= 1)
    for (int j = k >> 1; j > 0; j >>= 1) {
      if (j == 512) {
        if (vU > vL) { u64 tmp = vL; vL = vU; vU = tmp; }
      } else if (j >= 64) {
        __syncthreads();
        sbuf[t] = vL;
        if (k < 1024) sbuf[t + 512] = vU;
        __syncthreads();
        u64 oL = sbuf[t ^ j];
        bstep(vL, oL, t, k, j);
        if (k < 1024) {
          u64 oU = sbuf[(t ^ j) + 512];
          bstep(vU, oU, t + 512, k, j);
        }
      } else {
        bstep(vL, shflx64(vL, j), t, k, j);
        if (k < 1024) bstep(vU, shflx64(vU, j), t + 512, k, j);
      }
    }
}

// 1-elt/thread hybrid sort (used by k3b)
template <int S>
__device__ __forceinline__ void hybrid_sort(u64& v, u64* sbuf, int tid) {
  for (int k = 2; k <= S; k <<= 1)
    for (int j = k >> 1; j > 0; j >>= 1) {
      u64 o;
      if (j >= 64) {
        __syncthreads();
        sbuf[tid] = v;
        __syncthreads();
        o = sbuf[tid ^ j];
      } else {
        o = shflx64(v, j);
      }
      bool takeMax = (((tid & k) == 0) == ((tid & j) == 0));
      if (takeMax ? (o > v) : (o < v)) v = o;
    }
}

template <int T>
__device__ __forceinline__ void pick_threshold(u32* hist, int* partial, int* s_t, int K, int tid) {
  constexpr int G = 2048 / T;
  int ps = 0;
#pragma unroll
  for (int q = 0; q < G; ++q) ps += (int)hist[tid * G + q];
  partial[tid] = ps;
  for (int off = 1; off < T; off <<= 1) {
    __syncthreads();
    int v = partial[tid];
    if (tid + off < T) v += partial[tid + off];
    __syncthreads();
    partial[tid] = v;
  }
  if (tid == 0) *s_t = 0;
  __syncthreads();
  int sfx = partial[tid];
  int nxt = (tid == T - 1) ? 0 : partial[tid + 1];
  if (sfx >= K && nxt < K) {
    int acc = nxt;
    int bin;
    for (bin = tid * G + G - 1; bin > tid * G; --bin) {
      if (acc + (int)hist[bin] >= K) break;
      acc += (int)hist[bin];
    }
    *s_t = bin;
  }
  __syncthreads();
}

// exact RN(inter/denom) > 0.5 with guard band + rare exact-div fallback
// (reference RN op order preserved: denom = ((ai+aj) - inter) + 1e-9)
__device__ __forceinline__ bool iou_sup(float4 bi, float4 bj) {
  float ai = __fmul_rn(fmaxf(__fsub_rn(bi.z, bi.x), 0.f), fmaxf(__fsub_rn(bi.w, bi.y), 0.f));
  float aj = __fmul_rn(fmaxf(__fsub_rn(bj.z, bj.x), 0.f), fmaxf(__fsub_rn(bj.w, bj.y), 0.f));
  float ih = fmaxf(__fsub_rn(fminf(bi.z, bj.z), fmaxf(bi.x, bj.x)), 0.f);
  float iw = fmaxf(__fsub_rn(fminf(bi.w, bj.w), fmaxf(bi.y, bj.y)), 0.f);
  float inter = __fmul_rn(ih, iw);
  float denom = __fadd_rn(__fsub_rn(__fadd_rn(ai, aj), inter), 1e-9f);
  float diff = __fsub_rn(__fmul_rn(inter, 2.f), denom);
  if (fabsf(diff) > __fmul_rn(denom, 1e-6f)) return diff > 0.f;
  return __fdiv_rn(inter, denom) > 0.5f;
}

// ---------------- kernel 1: candidate compaction (per-class LDS buffers) ----------------
// key = score_bits<<32 | (~n & 0xFFFF)<<16 | c   (c constant within a class sort)
// Per passing score: one LDS atomic on cnt[c] + one LDS store (lgkmcnt path, leaves
// the vmcnt load pipeline free — round-4 lesson). Round-5 proven form.
__global__ __launch_bounds__(512) void k1_compact(const float* __restrict__ cls,
                                                  int* __restrict__ candCnt,
                                                  u64* __restrict__ cand) {
  __shared__ u64 bkeyc[N_CLS * SLOT];   // 30720 B
  __shared__ int cnt[N_CLS];
  __shared__ int cbase[N_CLS];

  int tid = threadIdx.x;
  int b = blockIdx.x / NGRP, g = blockIdx.x % NGRP;
  int n0 = g * P_BOXES;
  int nb = N_BOXES - n0;
  if (nb > P_BOXES) nb = P_BOXES;
  int nf4 = nb * (N_CLS / 4);
  const float4* src = (const float4*)(cls + ((size_t)b * N_BOXES + n0) * N_CLS);

  if (tid < N_CLS) cnt[tid] = 0;
  __syncthreads();

  for (int i = tid; i < nf4; i += 512) {
    float4 s4 = src[i];
    bool p0 = s4.x > PRE_THR, p1 = s4.y > PRE_THR, p2 = s4.z > PRE_THR, p3 = s4.w > PRE_THR;
    if (p0 | p1 | p2 | p3) {
      int nl = i / 20;               // 20 float4 per 80-class row
      int cb = (i - nl * 20) * 4;
      u64 pk = (u64)((((u32)(~(u32)(n0 + nl)) & 0xFFFFu) << 16));
      if (p0) {
        int s = atomicAdd(&cnt[cb + 0], 1);
        if (s < SLOT) bkeyc[(cb + 0) * SLOT + s] = ((u64)__float_as_uint(s4.x) << 32) | pk | (u32)(cb + 0);
      }
      if (p1) {
        int s = atomicAdd(&cnt[cb + 1], 1);
        if (s < SLOT) bkeyc[(cb + 1) * SLOT + s] = ((u64)__float_as_uint(s4.y) << 32) | pk | (u32)(cb + 1);
      }
      if (p2) {
        int s = atomicAdd(&cnt[cb + 2], 1);
        if (s < SLOT) bkeyc[(cb + 2) * SLOT + s] = ((u64)__float_as_uint(s4.z) << 32) | pk | (u32)(cb + 2);
      }
      if (p3) {
        int s = atomicAdd(&cnt[cb + 3], 1);
        if (s < SLOT) bkeyc[(cb + 3) * SLOT + s] = ((u64)__float_as_uint(s4.w) << 32) | pk | (u32)(cb + 3);
      }
    }
  }
  __syncthreads();
  if (tid < N_CLS) {
    int n = cnt[tid];
    if (n > SLOT) n = SLOT;
    cnt[tid] = n;
    cbase[tid] = n ? atomicAdd(&candCnt[b * N_CLS + tid], n) : 0;
  }
  __syncthreads();
  for (int i = tid; i < N_CLS * SLOT; i += 512) {
    int c = i / SLOT, s = i - c * SLOT;
    if (s < cnt[c]) {
      int pos = cbase[c] + s;
      if (pos < CAP) cand[(size_t)(b * N_CLS + c) * CAP + pos] = bkeyc[i];
    }
  }
}

// eager tiles: (jb, w), w <= jb, jb <= 4  (15 tiles), <=2 tiles/wave (proven balance)
__device__ const unsigned char TJB[15] = {0, 1,1, 2,2,2, 3,3,3,3, 4,4,4,4,4};
__device__ const unsigned char TW[15]  = {0, 0,1, 0,1,2, 0,1,2,3, 0,1,2,3,4};

#define COLS_STRIDE 320

// Round-3 proven form: LDS broadcast reads (bank-conflict-free, 0 measured
// conflicts) + areas[] LDS. Round-7 lesson: readlane broadcast costs more
// (SGPR operand limit forces v_mov copies; VGPR 36->64, occupancy -9pts).
template <bool DIAG>
__device__ __forceinline__ void mask_tile(const float4* bx, const float* areas, u64* cols,
                                          int jb, int w, int lane, int V) {
  int j = jb * 64 + lane;
  u64 sup = 0;
  if (j < V) {
    float4 bj = bx[j];
    float aj = areas[j];
    const float4* bp = bx + w * 64;
    const float* ap = areas + w * 64;
    u64 needs = 0;
#pragma unroll 16
    for (int il = 0; il < 64; ++il) {
      float4 bi = bp[il];  // immediate-offset ds_read_b128, same-address broadcast
      float ai = ap[il];
      float yy1 = fmaxf(bi.x, bj.x);
      float xx1 = fmaxf(bi.y, bj.y);
      float yy2 = fminf(bi.z, bj.z);
      float xx2 = fminf(bi.w, bj.w);
      float ih = fmaxf(__fsub_rn(yy2, yy1), 0.0f);
      float iw = fmaxf(__fsub_rn(xx2, xx1), 0.0f);
      float inter = __fmul_rn(ih, iw);
      float denom = __fadd_rn(__fsub_rn(__fadd_rn(ai, aj), inter), 1e-9f);
      float diff = __fsub_rn(__fmul_rn(inter, 2.0f), denom);
      bool fast = diff > 0.0f;
      bool nd = fabsf(diff) <= __fmul_rn(denom, 1e-6f);
      if (DIAG) { bool lt = il < lane; fast = fast && lt; nd = nd && lt; }
      sup |= fast ? (1ull << il) : 0ull;
      needs |= nd ? (1ull << il) : 0ull;
    }
    if (needs) {
      u64 nm = needs;
      while (nm) {
        int il = __builtin_ctzll(nm);
        nm &= nm - 1;
        if (iou_sup(bp[il], bj)) sup |= (1ull << il);
        else sup &= ~(1ull << il);
      }
    }
  }
  cols[w * COLS_STRIDE + jb * 64 + lane] = sup;
}

// common tail of a scan chunk: greedy in-chunk propagation + kept-key write
#define SCAN_TAIL(dstc)                                                            \
    u64 supmask = __ballot(sup);                                                   \
    u64 anysup = wave_or64(colw);                                                  \
    u64 rem = anysup & ~supmask;                                                   \
    while (rem) {                                                                  \
      int i = __builtin_ctzll(rem);                                                \
      rem &= rem - 1;                                                              \
      if (!((supmask >> i) & 1ull)) {                                              \
        supmask |= __ballot((int)((colw >> i) & 1ull));                            \
        rem &= ~supmask;                                                           \
      }                                                                            \
    }                                                                              \
    int lim = V - (dstc) * 64;                                                     \
    if (lim > 64) lim = 64;                                                        \
    u64 valid = (lim >= 64) ? ~0ull : ((1ull << lim) - 1ull);                      \
    u64 keptm = ~supmask & valid;                                                  \
    int rank = total + (int)__builtin_popcountll(keptm & ((1ull << lane) - 1ull)); \
    if (((keptm >> lane) & 1ull) && rank < MAX_DET) {                              \
      u64 key = sbuf[gj];                                                          \
      u32 sb = (u32)(key >> 32);                                                   \
      u32 n = (~(u32)(key >> 16)) & 0xFFFFu;                                       \
      u32 flat = (u32)(c * KCAND + gj);                                            \
      keptKeys[(size_t)bc * 512 + rank] =                                          \
          ((u64)sb << 32) | ((u64)((~flat) & 0xFFFFu) << 16) | (u64)n;             \
      atomicAdd(&imgHist[b * 2048 + bin_of(sb)], 1u);                              \
    }                                                                              \
    total += (int)__builtin_popcountll(keptm);                                     \
    kmreg[dstc] = keptm;

// cols-based chunk (dstc <= 4); dstc compile-time so kmreg stays in registers
#define SCAN_CHUNK(dstc)                                                           \
  if ((dstc) * 64 < V && total < MAX_DET) {                                        \
    int gj = (dstc) * 64 + lane;                                                   \
    bool sup = false;                                                              \
    _Pragma("unroll")                                                              \
    for (int src = 0; src < (dstc); ++src)                                         \
      if (cols[src * COLS_STRIDE + gj] & kmreg[src]) sup = true;                   \
    u64 colw = cols[(dstc) * COLS_STRIDE + gj];                                    \
    SCAN_TAIL(dstc)                                                                \
  }

// on-the-fly fallback chunk (dstc >= 5): almost always skipped (total >= 300)
#define SCAN_CHUNK_FB(dstc)                                                        \
  if ((dstc) * 64 < V && total < MAX_DET) {                                        \
    int gj = (dstc) * 64 + lane;                                                   \
    bool act = gj < V;                                                             \
    float4 bg = bx[act ? gj : 0];                                                  \
    bool sup = false;                                                              \
    u64 colw = 0;                                                                  \
    _Pragma("unroll")                                                              \
    for (int src = 0; src < (dstc); ++src) {                                       \
      u64 km = kmreg[src];                                                         \
      while (km) {                                                                 \
        int i = __builtin_ctzll(km);                                               \
        km &= km - 1;                                                              \
        if (act && iou_sup(bx[src * 64 + i], bg)) sup = true;                      \
      }                                                                            \
    }                                                                              \
    for (int il = 0; il < 64; ++il)                                                \
      if (il < lane && act && iou_sup(bx[(dstc) * 64 + il], bg)) colw |= (1ull << il); \
    SCAN_TAIL(dstc)                                                                \
  }

// ---------------- kernel 2: sort-all + NMS ----------------
__global__ __launch_bounds__(512) void k2_class(const float* __restrict__ boxes,
                                                const int* __restrict__ candCnt,
                                                const u64* __restrict__ cand,
                                                int* __restrict__ keptCnt,
                                                u64* __restrict__ keptKeys,
                                                u32* __restrict__ imgHist) {
  __shared__ u64 sbuf[1024];            // 8 KB
  __shared__ float4 bx[512];            // 8 KB
  __shared__ float areas[512];          // 2 KB
  __shared__ u64 cols[5 * COLS_STRIDE]; // 12.8 KB -> total ~31 KB, 5 blocks/CU
  int tid = threadIdx.x;
  int lane = tid & 63, wave = tid >> 6;
  int bc = blockIdx.x;
  int b = bc / N_CLS, c = bc % N_CLS;
  int m = candCnt[bc];
  if (m > CAP) m = CAP;
  const u64* my = cand + (size_t)bc * CAP;

  u64 vL = (tid < m) ? my[tid] : 0;
  u64 vU = (tid + 512 < m) ? my[tid + 512] : 0;
  sort1024_2elt(vL, vU, sbuf, tid);   // vL = rank-tid element (descending)

  int V = m < KCAND ? m : KCAND;
  __syncthreads();
  sbuf[tid] = vL;  // ranks 0..511 (only <V used)
  float4 bxv = make_float4(0.f, 0.f, 0.f, 0.f);
  float av = 0.f;
  if (tid < V) {
    u32 n = (~(u32)(vL >> 16)) & 0xFFFFu;
    bxv = *(const float4*)(boxes + ((size_t)b * N_BOXES + n) * 4);
    av = __fmul_rn(fmaxf(__fsub_rn(bxv.z, bxv.x), 0.f), fmaxf(__fsub_rn(bxv.w, bxv.y), 0.f));
  }
  bx[tid] = bxv;
  areas[tid] = av;
  __syncthreads();

  // 15 eager mask tiles over 8 waves (<=2 tiles/wave)
  for (int idx = wave; idx < 15; idx += 8) {
    int jb = TJB[idx], w = TW[idx];
    if (w == jb) mask_tile<true>(bx, areas, cols, jb, w, lane, V);
    else mask_tile<false>(bx, areas, cols, jb, w, lane, V);
  }
  __syncthreads();

  // greedy scan, wave 0: chunks 0-4 from cols, 5-7 on-the-fly (rarely reached)
  if (tid < 64) {
    u64 kmreg[8];
    int total = 0;
    SCAN_CHUNK(0)
    SCAN_CHUNK(1)
    SCAN_CHUNK(2)
    SCAN_CHUNK(3)
    SCAN_CHUNK(4)
    SCAN_CHUNK_FB(5)
    SCAN_CHUNK_FB(6)
    SCAN_CHUNK_FB(7)
    if (lane == 0) keptCnt[bc] = total < MAX_DET ? total : MAX_DET;
  }
}

// ---------------- kernel 3a: per-image threshold + parallel filter (64 blocks) ----------------
// 8 blocks/image; each computes the (identical, deterministic) threshold from the
// image histogram, filters its 1/8 slice of keptKeys into an LDS buffer, then does
// ONE global atomicAdd for its segment base and copies out. Key multiset per image
// identical to the old single-block filter; order irrelevant (k3b fully sorts).
__global__ __launch_bounds__(512) void k3a_filter(const int* __restrict__ keptCnt,
                                                  const u64* __restrict__ keptKeys,
                                                  const u32* __restrict__ imgHist,
                                                  int* __restrict__ imgCnt,
                                                  u64* __restrict__ imgCand) {
  __shared__ u32 hist[2048];
  __shared__ int partial[512];
  __shared__ int kcs[N_CLS];
  __shared__ u64 lbuf[1024];
  __shared__ int s_t, s_cnt, s_base;
  int tid = threadIdx.x;
  int b = blockIdx.x >> 3, part = blockIdx.x & 7;
  for (int i = tid; i < 2048; i += 512) hist[i] = imgHist[b * 2048 + i];
  if (tid < N_CLS) kcs[tid] = keptCnt[b * N_CLS + tid];
  if (tid == 0) s_cnt = 0;
  __syncthreads();
  pick_threshold<512>(hist, partial, &s_t, MAX_DET, tid);
  int t = s_t;
  const u64* kk = keptKeys + (size_t)b * N_CLS * 512;
  int i0 = part * (N_CLS * 512 / 8);      // 5120 per part
  for (int q = 0; q < (N_CLS * 512 / 8); q += 512) {
    int idx = i0 + q + tid;
    int cc = idx >> 9, k = idx & 511;
    if (k < kcs[cc]) {
      u64 key = kk[(size_t)cc * 512 + k];
      if (bin_of((u32)(key >> 32)) >= t) {
        int p = atomicAdd(&s_cnt, 1);
        if (p < 1024) lbuf[p] = key;
      }
    }
  }
  __syncthreads();
  int n = s_cnt < 1024 ? s_cnt : 1024;
  if (tid == 0) s_base = n ? atomicAdd(&imgCnt[b], n) : 0;
  __syncthreads();
  int base = s_base;
  for (int i = tid; i < n; i += 512) {
    int pos = base + i;
    if (pos < 1024) imgCand[(size_t)b * 1024 + pos] = lbuf[i];
  }
}

// ---------------- kernel 3b: per-image sort + emit (8 blocks) ----------------
__global__ __launch_bounds__(1024) void k3b_emit(const float* __restrict__ boxes,
                                                 const int* __restrict__ imgCnt,
                                                 const u64* __restrict__ imgCand,
                                                 float* __restrict__ out) {
  __shared__ u64 sbuf[1024];
  int tid = threadIdx.x;
  int b = blockIdx.x;
  int cnt = imgCnt[b];
  if (cnt > 1024) cnt = 1024;
  u64 v = (tid < cnt) ? imgCand[(size_t)b * 1024 + tid] : 0;
  hybrid_sort<1024>(v, sbuf, tid);

  int V = cnt < MAX_DET ? cnt : MAX_DET;
  if (tid < MAX_DET) {
    float o0 = -1.f, o1 = -1.f, o2 = -1.f, o3 = -1.f, osc = -1.f, olb = -1.f;
    if (tid < V) {
      u32 sb = (u32)(v >> 32);
      u32 flat = (~((u32)(v >> 16))) & 0xFFFFu;
      u32 n = (u32)v & 0xFFFFu;
      const float* bp = boxes + ((size_t)b * N_BOXES + n) * 4;
      o0 = bp[0]; o1 = bp[1]; o2 = bp[2]; o3 = bp[3];
      osc = __uint_as_float(sb);
      olb = (float)(flat / KCAND);
    }
    size_t bs = (size_t)b * MAX_DET + tid;
    out[bs * 4 + 0] = o0;
    out[bs * 4 + 1] = o1;
    out[bs * 4 + 2] = o2;
    out[bs * 4 + 3] = o3;
    out[(size_t)N_IMG * MAX_DET * 4 + bs] = osc;
    out[(size_t)N_IMG * MAX_DET * 5 + bs] = olb;
  }
}

extern "C" void kernel_launch(void* const* d_in, const int* in_sizes, int n_in,
                              void* d_out, int out_size, void* d_ws, size_t ws_size,
                              hipStream_t stream) {
  const float* boxes = (const float*)d_in[0];
  const float* cls = (const float*)d_in[1];
  float* out = (float*)d_out;
  char* ws = (char*)d_ws;
  int* candCnt = (int*)(ws + OFF_CANDCNT);
  int* keptCnt = (int*)(ws + OFF_KEPTCNT);
  int* imgCnt = (int*)(ws + OFF_IMGCNT);
  u32* imgHist = (u32*)(ws + OFF_IMGHIST);
  u64* keptKeys = (u64*)(ws + OFF_KEPTKEYS);
  u64* cand = (u64*)(ws + OFF_CAND);
  u64* imgCand = (u64*)(ws + OFF_IMGCAND);

  hipMemsetAsync(ws, 0, 73728, stream);  // candCnt + keptCnt + imgCnt + imgHist

  k1_compact<<<N_IMG * NGRP, 512, 0, stream>>>(cls, candCnt, cand);
  k2_class<<<N_IMG * N_CLS, 512, 0, stream>>>(boxes, candCnt, cand, keptCnt, keptKeys, imgHist);
  k3a_filter<<<N_IMG * 8, 512, 0, stream>>>(keptCnt, keptKeys, imgHist, imgCnt, imgCand);
  k3b_emit<<<N_IMG, 1024, 0, stream>>>(boxes, imgCnt, imgCand, out);
}